// Round 6
// baseline (319569.043 us; speedup 1.0000x reference)
//
#include <hip/hip_runtime.h>

#define IDIM  64
#define HDIM  512
#define T_LEN 65536
#define NWG   64
#define NTHR  1024

// Tagged hidden state: high 32 bits = tick tag, low 32 bits = float payload.
// The tag check doubles as the device-wide barrier (data+signal in one 8B word).
__device__ unsigned long long g_h1[2][HDIM];
__device__ unsigned long long g_h2[2][HDIM];

__device__ __forceinline__ unsigned long long pack(float v, int k) {
  return ((unsigned long long)(unsigned)k << 32) | (unsigned long long)__float_as_uint(v);
}

__global__ void lstm_init() {
  int t = threadIdx.x;
  for (int e = t; e < HDIM; e += blockDim.x) {
    g_h1[0][e] = 0xFFFFFFFF00000000ull;  // tag=-1, val=0
    g_h1[1][e] = 0xFFFFFFFF00000000ull;  // read at tick 0 (expect -1)
    g_h2[0][e] = 0xFFFFFFFF00000000ull;  // read at tick 0 (expect -1)
    g_h2[1][e] = 0x0000000000000000ull;  // tag=0,val=0: h2(-1), read at tick 1
  }
}

__global__ __launch_bounds__(NTHR)
__attribute__((amdgpu_waves_per_eu(4, 4)))   // 1024-thr block = 4 waves/EU resident; 128-VGPR budget
void lstm_main(
    const float* __restrict__ x_seq,
    const float* __restrict__ W_ih1, const float* __restrict__ W_hh1,
    const float* __restrict__ b_ih1, const float* __restrict__ b_hh1,
    const float* __restrict__ W_ih2, const float* __restrict__ W_hh2,
    const float* __restrict__ b_ih2, const float* __restrict__ b_hh2,
    const float* __restrict__ W_out, const float* __restrict__ b_out,
    float* __restrict__ out)
{
  const int wg   = blockIdx.x;
  const int tid  = threadIdx.x;
  const int wave = tid >> 6;      // 0..15
  const int role = wave >> 3;     // 0 = layer1 (waves 0-7), 1 = layer2 (waves 8-15)
  const int lane = tid & 63;
  const int g    = lane >> 4;     // gate 0..3 (i,f,g,o)
  const int s    = lane & 15;     // strip 0..15
  const int j    = wg * 8 + (wave & 7);   // owned hidden index for this (j,layer) wave
  const int r    = g * HDIM + j;          // gate row in [0,2048)

  // ---- weights -> VGPRs: ONE array, role-dependent contents (max 64 live floats) ----
  float w[64];
  if (role == 0) {
    // layer1 row = [W_hh1[r,0:512] | W_ih1[r,0:64]]; lane covers e = s*36 .. s*36+35
#pragma unroll
    for (int m = 0; m < 36; ++m) {
      int e = s * 36 + m;
      w[m] = (e < HDIM) ? W_hh1[(size_t)r * HDIM + e]
                        : W_ih1[(size_t)r * IDIM + (e - HDIM)];
    }
#pragma unroll
    for (int m = 0; m < 36; ++m) asm volatile("" : "+v"(w[m]));  // forbid remat
  } else {
    // layer2 row = [W_ih2[r,0:512] | W_hh2[r,0:512]]; lane covers e = s*64 .. s*64+63,
    // chunk-rotated by s to avoid LDS bank conflicts on the stride-256B read pattern.
#pragma unroll
    for (int c = 0; c < 16; ++c) {
#pragma unroll
      for (int i = 0; i < 4; ++i) {
        int er = s * 64 + ((c + s) & 15) * 4 + i;   // 0..1023
        w[c * 4 + i] = (er < HDIM) ? W_ih2[(size_t)r * HDIM + er]
                                   : W_hh2[(size_t)r * HDIM + (er - HDIM)];
      }
    }
#pragma unroll
    for (int m = 0; m < 64; ++m) asm volatile("" : "+v"(w[m]));  // forbid remat
  }
  // single per-thread bias: gate g of row j for this layer
  const float bsel = (role == 0) ? (b_ih1[r] + b_hh1[r]) : (b_ih2[r] + b_hh2[r]);

  // this thread's ONE poll slot: tid<512 -> h1[tid], else h2[tid-512]
  const int hslot = (tid < HDIM) ? tid : tid - HDIM;

  float cst = 0.f;                 // cell state for owned (j, layer)
  int bud = 1 << 24;               // GLOBAL spin budget: fail fast, not per-tick

  __shared__ __align__(16) float vec[2][HDIM + IDIM + HDIM]; // [h1_prev | x_k | h2_prev] x2

  for (int k = 0; k <= T_LEN; ++k) {
    const unsigned expect = (unsigned)(k - 1);
    const int p1  = (k + 1) & 1;  // h1(k-1) lives here (tag k-1)
    const int p2  = k & 1;        // h2(k-2) lives here (tag k-1)
    const int buf = k & 1;

    // x load issued before the poll so its latency hides under it
    float xv = 0.f;
    if (tid < IDIM && k < T_LEN) xv = x_seq[(size_t)k * IDIM + tid];

    // ---- per-thread spin on this thread's single slot (sleep-backoff on miss) ----
    unsigned long long* slotp = (tid < HDIM) ? &g_h1[p1][hslot] : &g_h2[p2][hslot];
    unsigned long long a = __hip_atomic_load(slotp, __ATOMIC_RELAXED, __HIP_MEMORY_SCOPE_AGENT);
    while ((unsigned)(a >> 32) != expect && --bud > 0) {
      __builtin_amdgcn_s_sleep(1);   // ~64cy backoff: cuts MALL poll pressure
      a = __hip_atomic_load(slotp, __ATOMIC_RELAXED, __HIP_MEMORY_SCOPE_AGENT);
    }

    // fill: h1 -> vec[0..511], x -> vec[512..575], h2 -> vec[576..1087]
    if (tid < HDIM) vec[buf][tid] = __uint_as_float((unsigned)a);
    else            vec[buf][IDIM + tid] = __uint_as_float((unsigned)a);
    if (tid < IDIM) vec[buf][HDIM + tid] = xv;
    __syncthreads();   // only barrier per tick; vec is double-buffered

    // ---- compute: role 0 = layer1 step k; role 1 = layer2 step k-1 ----
    const bool active = (role == 0) ? (k < T_LEN) : (k > 0);
    if (active) {
      float acc = 0.f;
      if (role == 0) {
#pragma unroll
        for (int mc = 0; mc < 9; ++mc) {
          const float4 hv = *reinterpret_cast<const float4*>(&vec[buf][s * 36 + mc * 4]);
          acc = fmaf(w[mc * 4 + 0], hv.x, acc);
          acc = fmaf(w[mc * 4 + 1], hv.y, acc);
          acc = fmaf(w[mc * 4 + 2], hv.z, acc);
          acc = fmaf(w[mc * 4 + 3], hv.w, acc);
        }
      } else {
        const int vb = (s < 8) ? 0 : IDIM;  // skip the x-gap for the h2 half
#pragma unroll
        for (int c = 0; c < 16; ++c) {
          const int off = s * 64 + ((c + s) & 15) * 4 + vb;
          const float4 hv = *reinterpret_cast<const float4*>(&vec[buf][off]);
          acc = fmaf(w[c * 4 + 0], hv.x, acc);
          acc = fmaf(w[c * 4 + 1], hv.y, acc);
          acc = fmaf(w[c * 4 + 2], hv.z, acc);
          acc = fmaf(w[c * 4 + 3], hv.w, acc);
        }
      }
      acc += __shfl_xor(acc, 8, 16);
      acc += __shfl_xor(acc, 4, 16);
      acc += __shfl_xor(acc, 2, 16);
      acc += __shfl_xor(acc, 1, 16);

      // per-group activation: group g activates ITS gate, then broadcast activated values.
      // tanh(x) = 2*sigmoid(2x) - 1 (exact identity) -> single sigmoid path per lane.
      const float xs  = acc + bsel;
      const float xin = (g == 2) ? 2.f * xs : xs;
      const float sgm = 1.f / (1.f + expf(-xin));
      const float act = (g == 2) ? 2.f * sgm - 1.f : sgm;
      const float ai = __shfl(act, 0, 64);
      const float af = __shfl(act, 16, 64);
      const float ag = __shfl(act, 32, 64);
      const float ao = __shfl(act, 48, 64);
      cst = af * cst + ai * ag;
      const float tc = 2.f / (1.f + expf(-2.f * cst)) - 1.f;   // tanh(cst)
      const float hv = ao * tc;
      if (lane == 0) {
        if (role == 0)
          __hip_atomic_store(&g_h1[k & 1][j], pack(hv, k),
                             __ATOMIC_RELAXED, __HIP_MEMORY_SCOPE_AGENT);
        else
          __hip_atomic_store(&g_h2[(k + 1) & 1][j], pack(hv, k),
                             __ATOMIC_RELAXED, __HIP_MEMORY_SCOPE_AGENT);
      }
    }
    // no trailing barrier: double-buffered vec + per-tick barrier keep WAR safe
  }

  // ---- final output: out = W_out . h2(T-1) + b_out ----
  if (wg == 0 && wave == 0) {
    float acc = 0.f;
    int bud2 = 1 << 24;
#pragma unroll
    for (int e = 0; e < HDIM / 64; ++e) {
      const int idx = lane + e * 64;
      unsigned long long u;
      do {
        u = __hip_atomic_load(&g_h2[1][idx], __ATOMIC_RELAXED, __HIP_MEMORY_SCOPE_AGENT);
      } while ((unsigned)(u >> 32) != (unsigned)T_LEN && --bud2 > 0);
      acc = fmaf(W_out[idx], __uint_as_float((unsigned)u), acc);
    }
    acc += __shfl_xor(acc, 32, 64);
    acc += __shfl_xor(acc, 16, 64);
    acc += __shfl_xor(acc, 8, 64);
    acc += __shfl_xor(acc, 4, 64);
    acc += __shfl_xor(acc, 2, 64);
    acc += __shfl_xor(acc, 1, 64);
    if (lane == 0) out[0] = acc + b_out[0];
  }
}

extern "C" void kernel_launch(void* const* d_in, const int* in_sizes, int n_in,
                              void* d_out, int out_size, void* d_ws, size_t ws_size,
                              hipStream_t stream) {
  const float* x_seq = (const float*)d_in[0];
  const float* W_ih1 = (const float*)d_in[1];
  const float* W_hh1 = (const float*)d_in[2];
  const float* b_ih1 = (const float*)d_in[3];
  const float* b_hh1 = (const float*)d_in[4];
  const float* W_ih2 = (const float*)d_in[5];
  const float* W_hh2 = (const float*)d_in[6];
  const float* b_ih2 = (const float*)d_in[7];
  const float* b_hh2 = (const float*)d_in[8];
  const float* W_out = (const float*)d_in[9];
  const float* b_out = (const float*)d_in[10];
  float* out = (float*)d_out;

  hipLaunchKernelGGL(lstm_init, dim3(1), dim3(256), 0, stream);
  hipLaunchKernelGGL(lstm_main, dim3(NWG), dim3(NTHR), 0, stream,
                     x_seq, W_ih1, W_hh1, b_ih1, b_hh1,
                     W_ih2, W_hh2, b_ih2, b_hh2, W_out, b_out, out);
}

// Round 7
// 155221.924 us; speedup vs baseline: 2.0588x; 2.0588x over previous
//
#include <hip/hip_runtime.h>

#define IDIM  64
#define HDIM  512
#define T_LEN 65536
#define NWG   128
#define NTHR  512
#define NCHUNK (NWG * 3)   // 384 self-validating 16B chunks per tick-buffer

typedef unsigned int u32x4 __attribute__((ext_vector_type(4)));

// Per-WG publish line: 3 x 16B chunks {tag, f, f, f}, padded to 128B.
// chunk0={tag,h1[0..2]} chunk1={tag,h1[3],h2[0..1]} chunk2={tag,h2[2..3],0}
__device__ u32x4 g_post[2][NWG][8];

__device__ __forceinline__ u32x4 load_chunk(const u32x4* p) {
  u32x4 r;
  unsigned long long a = (unsigned long long)p;
  asm volatile("global_load_dwordx4 %0, %1, off sc0 sc1\n\t"
               "s_waitcnt vmcnt(0)"
               : "=v"(r) : "v"(a) : "memory");
  return r;
}
__device__ __forceinline__ void store_chunk(u32x4* p, u32x4 v) {
  unsigned long long a = (unsigned long long)p;
  asm volatile("global_store_dwordx4 %0, %1, off sc0 sc1"
               :: "v"(a), "v"(v) : "memory");
}

__global__ void lstm_init() {
  int t = threadIdx.x;
  for (int w = t; w < NWG; w += blockDim.x) {
    for (int i = 0; i < 3; ++i) {
      u32x4 m1 = {0xFFFFFFFFu, 0u, 0u, 0u};  // tag=-1, vals=0 : read at tick 0
      u32x4 nv = {0xFFFFFFFEu, 0u, 0u, 0u};  // never-match until overwritten at tick 0
      g_post[1][w][i] = m1;
      g_post[0][w][i] = nv;
    }
  }
}

__global__ __launch_bounds__(NTHR)
__attribute__((amdgpu_waves_per_eu(2, 2)))   // round-5 shape: VGPR=88, weights resident
void lstm_main(
    const float* __restrict__ x_seq,
    const float* __restrict__ W_ih1, const float* __restrict__ W_hh1,
    const float* __restrict__ b_ih1, const float* __restrict__ b_hh1,
    const float* __restrict__ W_ih2, const float* __restrict__ W_hh2,
    const float* __restrict__ b_ih2, const float* __restrict__ b_hh2,
    const float* __restrict__ W_out, const float* __restrict__ b_out,
    float* __restrict__ out)
{
  const int wg   = blockIdx.x;
  const int tid  = threadIdx.x;
  const int wave = tid >> 6;      // 0..7
  const int role = wave >> 2;     // 0 = layer1, 1 = layer2
  const int lane = tid & 63;
  const int g    = lane >> 4;     // gate 0..3 (i,f,g,o)
  const int s    = lane & 15;     // strip 0..15
  const int j    = wg * 4 + (wave & 3);   // owned hidden index for this (j,layer) wave
  const int r    = g * HDIM + j;          // gate row in [0,2048)

  // ---- weights -> VGPRs: ONE array, role-dependent contents (max 64 live floats) ----
  float w[64];
  if (role == 0) {
#pragma unroll
    for (int m = 0; m < 36; ++m) {
      int e = s * 36 + m;
      w[m] = (e < HDIM) ? W_hh1[(size_t)r * HDIM + e]
                        : W_ih1[(size_t)r * IDIM + (e - HDIM)];
    }
#pragma unroll
    for (int m = 0; m < 36; ++m) asm volatile("" : "+v"(w[m]));  // forbid remat
  } else {
#pragma unroll
    for (int c = 0; c < 16; ++c) {
#pragma unroll
      for (int i = 0; i < 4; ++i) {
        int er = s * 64 + ((c + s) & 15) * 4 + i;   // 0..1023
        w[c * 4 + i] = (er < HDIM) ? W_ih2[(size_t)r * HDIM + er]
                                   : W_hh2[(size_t)r * HDIM + (er - HDIM)];
      }
    }
#pragma unroll
    for (int m = 0; m < 64; ++m) asm volatile("" : "+v"(w[m]));  // forbid remat
  }
  const float bsel = (role == 0) ? (b_ih1[r] + b_hh1[r]) : (b_ih2[r] + b_hh2[r]);

  float cst = 0.f;                 // cell state for owned (j, layer)
  int bud = 1 << 24;               // GLOBAL spin budget: fail fast, not per-tick

  __shared__ __align__(16) float vec[2][HDIM + IDIM + HDIM]; // [h1 | x | h2] x2
  __shared__ float hbuf[8];        // per-wave h gather for packed publish

  // chunk-poll mapping: threads 0..383 each own one chunk
  const int cw = tid / 3;          // line (producer WG) index
  const int ci = tid - cw * 3;     // chunk index within line

  for (int k = 0; k <= T_LEN; ++k) {
    const unsigned expect = (unsigned)(k - 1);
    const int pb  = (k + 1) & 1;  // buffer holding tag k-1
    const int buf = k & 1;

    // ---- fill: 384 poll threads + 64 x-threads ----
    if (tid < NCHUNK) {
      const u32x4* src = &g_post[pb][cw][ci];
      u32x4 ch = load_chunk(src);
      while (ch[0] != expect && --bud > 0) ch = load_chunk(src);
      const float f0 = __uint_as_float(ch[1]);
      const float f1 = __uint_as_float(ch[2]);
      const float f2 = __uint_as_float(ch[3]);
      const int b1 = cw * 4;                 // h1 dest base
      const int b2 = HDIM + IDIM + cw * 4;   // h2 dest base
      if (ci == 0)      { vec[buf][b1+0] = f0; vec[buf][b1+1] = f1; vec[buf][b1+2] = f2; }
      else if (ci == 1) { vec[buf][b1+3] = f0; vec[buf][b2+0] = f1; vec[buf][b2+1] = f2; }
      else              { vec[buf][b2+2] = f0; vec[buf][b2+3] = f1; }
    } else if (tid < NCHUNK + IDIM) {
      if (k < T_LEN)
        vec[buf][HDIM + (tid - NCHUNK)] = x_seq[(size_t)k * IDIM + (tid - NCHUNK)];
    }
    __syncthreads();   // barrier1: vec[buf] complete

    // ---- compute: role 0 = layer1 step k; role 1 = layer2 step k-1 ----
    float hv = 0.f;
    const bool active = (role == 0) ? (k < T_LEN) : (k > 0);
    if (active) {
      float acc = 0.f;
      if (role == 0) {
#pragma unroll
        for (int mc = 0; mc < 9; ++mc) {
          const float4 hvv = *reinterpret_cast<const float4*>(&vec[buf][s * 36 + mc * 4]);
          acc = fmaf(w[mc * 4 + 0], hvv.x, acc);
          acc = fmaf(w[mc * 4 + 1], hvv.y, acc);
          acc = fmaf(w[mc * 4 + 2], hvv.z, acc);
          acc = fmaf(w[mc * 4 + 3], hvv.w, acc);
        }
      } else {
        const int vb = (s < 8) ? 0 : IDIM;  // skip the x-gap for the h2 half
#pragma unroll
        for (int c = 0; c < 16; ++c) {
          const int off = s * 64 + ((c + s) & 15) * 4 + vb;
          const float4 hvv = *reinterpret_cast<const float4*>(&vec[buf][off]);
          acc = fmaf(w[c * 4 + 0], hvv.x, acc);
          acc = fmaf(w[c * 4 + 1], hvv.y, acc);
          acc = fmaf(w[c * 4 + 2], hvv.z, acc);
          acc = fmaf(w[c * 4 + 3], hvv.w, acc);
        }
      }
      acc += __shfl_xor(acc, 8, 16);
      acc += __shfl_xor(acc, 4, 16);
      acc += __shfl_xor(acc, 2, 16);
      acc += __shfl_xor(acc, 1, 16);

      // per-group activation (tanh via 2*sigmoid(2x)-1), then broadcast activated gates
      const float xs  = acc + bsel;
      const float xin = (g == 2) ? 2.f * xs : xs;
      const float sgm = 1.f / (1.f + expf(-xin));
      const float act = (g == 2) ? 2.f * sgm - 1.f : sgm;
      const float ai = __shfl(act, 0, 64);
      const float af = __shfl(act, 16, 64);
      const float ag = __shfl(act, 32, 64);
      const float ao = __shfl(act, 48, 64);
      cst = af * cst + ai * ag;
      const float tc = 2.f / (1.f + expf(-2.f * cst)) - 1.f;   // tanh(cst)
      hv = ao * tc;
    }
    if (lane == 0) hbuf[wave] = hv;   // waves 0-3: h1[j], waves 4-7: h2[j]
    __syncthreads();   // barrier2: hbuf complete

    // ---- packed publish: 3 contiguous 16B self-tagged chunks per WG ----
    if (tid < 3) {
      const unsigned tag = (unsigned)k;
      u32x4 o;
      if (tid == 0) {
        o[0]=tag; o[1]=__float_as_uint(hbuf[0]); o[2]=__float_as_uint(hbuf[1]); o[3]=__float_as_uint(hbuf[2]);
      } else if (tid == 1) {
        o[0]=tag; o[1]=__float_as_uint(hbuf[3]); o[2]=__float_as_uint(hbuf[4]); o[3]=__float_as_uint(hbuf[5]);
      } else {
        o[0]=tag; o[1]=__float_as_uint(hbuf[6]); o[2]=__float_as_uint(hbuf[7]); o[3]=0u;
      }
      store_chunk(&g_post[buf][wg][tid], o);
    }
  }

  // ---- final output: out = W_out . h2(T-1) + b_out ----
  if (wg == 0 && wave == 0) {
    float acc = 0.f;
    int bud2 = 1 << 24;
#pragma unroll
    for (int rep = 0; rep < 2; ++rep) {
      const int w2 = lane + rep * 64;   // line index 0..127
      const u32x4* p1 = &g_post[0][w2][1];   // {tag, h1[3], h2[0], h2[1]}
      const u32x4* p2 = &g_post[0][w2][2];   // {tag, h2[2], h2[3], 0}
      u32x4 c1 = load_chunk(p1);
      while (c1[0] != (unsigned)T_LEN && --bud2 > 0) c1 = load_chunk(p1);
      u32x4 c2 = load_chunk(p2);
      while (c2[0] != (unsigned)T_LEN && --bud2 > 0) c2 = load_chunk(p2);
      acc = fmaf(W_out[4 * w2 + 0], __uint_as_float(c1[2]), acc);
      acc = fmaf(W_out[4 * w2 + 1], __uint_as_float(c1[3]), acc);
      acc = fmaf(W_out[4 * w2 + 2], __uint_as_float(c2[1]), acc);
      acc = fmaf(W_out[4 * w2 + 3], __uint_as_float(c2[2]), acc);
    }
    acc += __shfl_xor(acc, 32, 64);
    acc += __shfl_xor(acc, 16, 64);
    acc += __shfl_xor(acc, 8, 64);
    acc += __shfl_xor(acc, 4, 64);
    acc += __shfl_xor(acc, 2, 64);
    acc += __shfl_xor(acc, 1, 64);
    if (lane == 0) out[0] = acc + b_out[0];
  }
}

extern "C" void kernel_launch(void* const* d_in, const int* in_sizes, int n_in,
                              void* d_out, int out_size, void* d_ws, size_t ws_size,
                              hipStream_t stream) {
  const float* x_seq = (const float*)d_in[0];
  const float* W_ih1 = (const float*)d_in[1];
  const float* W_hh1 = (const float*)d_in[2];
  const float* b_ih1 = (const float*)d_in[3];
  const float* b_hh1 = (const float*)d_in[4];
  const float* W_ih2 = (const float*)d_in[5];
  const float* W_hh2 = (const float*)d_in[6];
  const float* b_ih2 = (const float*)d_in[7];
  const float* b_hh2 = (const float*)d_in[8];
  const float* W_out = (const float*)d_in[9];
  const float* b_out = (const float*)d_in[10];
  float* out = (float*)d_out;

  hipLaunchKernelGGL(lstm_init, dim3(1), dim3(256), 0, stream);
  hipLaunchKernelGGL(lstm_main, dim3(NWG), dim3(NTHR), 0, stream,
                     x_seq, W_ih1, W_hh1, b_ih1, b_hh1,
                     W_ih2, W_hh2, b_ih2, b_hh2, W_out, b_out, out);
}